// Round 14
// baseline (49.968 us; speedup 1.0000x reference)
//
#include <hip/hip_runtime.h>

// ---------------------------------------------------------------------------
// ConvBlock: y = clip(BN(tr(conv3x3(x^2, Wconv))), -1, 1)
// Wconv[oc][c][di][dj] = weight[oc>>3][(c*9+3di+dj)>>3][(oc-(c*9+3di+dj))&7]
// GEMM: A = Wconv (M=64 oc), B = im2col(x^2) (N=65536 px), K=576.
// bf16 MFMA 32x32x16, 3-pass hi/lo split.
// Round 14: DECORRELATION. 1-row tiles, 128-thr blocks (2 waves, merge-free
// full-K), grid (32,64)=2048 blocks -> ~6 resident/CU with churn so blocks
// occupy different phases (stage/MFMA/epilogue overlap across blocks).
// setprio(1) around MFMA cluster. 3 barriers. Same proven math as r13.
// ---------------------------------------------------------------------------

#define A_MORR 0.8578f
#define R_MORR 0.8578f
#define TR_C1 (A_MORR * A_MORR + R_MORR * R_MORR)
#define TR_C2 (-2.0f * A_MORR * R_MORR)
#define TR_C3 (1.0f + (A_MORR * R_MORR) * (A_MORR * R_MORR))
#define BN_EPS 1e-5f

#define NPIX 65536
#define X2_LO 13056          // 3*34*128: lo plane offset
#define SMEM_BYTES 26112
#define NBLK 2048            // conv grid size (32 x 64)

typedef __attribute__((ext_vector_type(8))) short bf16x8;
typedef __attribute__((ext_vector_type(16))) float f32x16;

__device__ __forceinline__ void bf16split(float s, unsigned short& h, unsigned short& l) {
    union { float f; unsigned u; } cv; cv.f = s;
    unsigned r = (cv.u + 0x7fffu + ((cv.u >> 16) & 1u)) & 0xffff0000u;
    h = (unsigned short)(r >> 16);
    union { unsigned u; float f; } hv; hv.u = r;
    float lo = s - hv.f;
    cv.f = lo;
    unsigned r2 = cv.u + 0x7fffu + ((cv.u >> 16) & 1u);
    l = (unsigned short)(r2 >> 16);
}

// ---------------------------------------------------------------------------
// Kernel A: fragment-ready bf16 hi/lo weights.
// wfrag[off*8 + ks*2 + mt][prec][lane][8ch] : 72 * 2048 B
// ---------------------------------------------------------------------------
__global__ __launch_bounds__(256) void prep_kernel(const float* __restrict__ w,
                                                   char* __restrict__ wfrag) {
    int gtid = blockIdx.x * 256 + threadIdx.x;
    if (gtid < 36864) {
        int j    = gtid & 7;
        int lane = (gtid >> 3) & 63;
        int okm  = gtid >> 9;
        int mt   = okm & 1;
        int ks   = (okm >> 1) & 3;
        int off  = okm >> 3;
        int oc   = mt * 32 + (lane & 31);
        int c    = ks * 16 + (lane >> 5) * 8 + j;
        int kg   = c * 9 + off;
        float val = w[(oc >> 3) * 576 + (kg >> 3) * 8 + ((oc - kg) & 7)];
        unsigned short h, l;
        bf16split(val, h, l);
        ((unsigned short*)(wfrag + okm * 2048))[lane * 8 + j] = h;
        ((unsigned short*)(wfrag + okm * 2048 + 1024))[lane * 8 + j] = l;
    }
}

// ---------------------------------------------------------------------------
// Kernel B: 1-row-tile merge-free MFMA conv + tr; per-block BN partials.
// grid (32,64) = 2048 blocks, block 128 (2 waves: wmt). Wave: 32 oc x 32 px
// (output row rt), FULL K=576. LDS x2: [3 rows][34 cols][64 ch] bf16 hi+lo,
// granule swizzle g = q^(c&7):
//   byte(r,c,ch) = ((r*34+c)<<7) + (((ch>>3)^(c&7))<<4) + (ch&7)*2 (+X2_LO lo)
// Staging: thread = (col-pair, ch-octet): float2 loads (coalesced 128B per
// 16-lane group), two conflict-free b128 granule writes per row/plane.
// ---------------------------------------------------------------------------
__global__ __launch_bounds__(128, 4) void conv_kernel(const float* __restrict__ x,
                                                      const char* __restrict__ wfrag,
                                                      float* __restrict__ out,
                                                      float* __restrict__ partials) {
    const int rt  = blockIdx.x;          // output row 0..31
    const int b   = blockIdx.y;
    const int bid = b * 32 + rt;         // 0..2047
    const int tid = threadIdx.x;

    const int lane = tid & 63;
    const int wmt  = tid >> 6;           // 0..1 (oc half)
    const int col  = lane & 31;
    const int hs   = lane >> 5;

    __shared__ __align__(16) char smem[SMEM_BYTES];

    // ---- zero halo cols (c=0, c=33): 3 rows x 2 cols x 8 q x 2 planes ----
    if (tid < 96) {
        int pr = tid & 1;
        int q  = (tid >> 1) & 7;
        int rc = tid >> 4;               // 0..5
        int r  = rc >> 1;
        int cc = (rc & 1) ? 33 : 0;
        int g  = q ^ (cc & 7);
        *(uint4*)(smem + pr * X2_LO + ((r * 34 + cc) << 7) + (g << 4)) = uint4{0, 0, 0, 0};
    }

    // ---- stage x^2 hi/lo: thread = (col-pair co2, octet qg), rows rt-1..rt+1 ----
    {
        const int co2 = tid & 15;        // covers image cols 2co2, 2co2+1
        const int qg  = tid >> 4;        // channel octet 0..7
        const int cA  = 1 + co2 * 2;
        const int cB  = cA + 1;
        const int gwA = (qg ^ (cA & 7)) << 4;
        const int gwB = (qg ^ (cB & 7)) << 4;
        const float* xb = x + (size_t)(b * 64 + qg * 8) * 1024 + co2 * 2;
#pragma unroll
        for (int r = 0; r < 3; ++r) {
            int gr = rt - 1 + r;
            float2 v2[8];
#pragma unroll
            for (int j = 0; j < 8; ++j) v2[j] = float2{0.f, 0.f};
            if (gr >= 0 && gr < 32) {
#pragma unroll
                for (int j = 0; j < 8; ++j)
                    v2[j] = *(const float2*)(xb + j * 1024 + gr * 32);
            }
            unsigned hA[4], lA[4], hB[4], lB[4];
#pragma unroll
            for (int p = 0; p < 4; ++p) {
                unsigned short h0, l0, h1, l1;
                float sa0 = v2[2 * p].x * v2[2 * p].x;
                float sa1 = v2[2 * p + 1].x * v2[2 * p + 1].x;
                bf16split(sa0, h0, l0);
                bf16split(sa1, h1, l1);
                hA[p] = (unsigned)h0 | ((unsigned)h1 << 16);
                lA[p] = (unsigned)l0 | ((unsigned)l1 << 16);
                float sb0 = v2[2 * p].y * v2[2 * p].y;
                float sb1 = v2[2 * p + 1].y * v2[2 * p + 1].y;
                bf16split(sb0, h0, l0);
                bf16split(sb1, h1, l1);
                hB[p] = (unsigned)h0 | ((unsigned)h1 << 16);
                lB[p] = (unsigned)l0 | ((unsigned)l1 << 16);
            }
            char* dA = smem + ((r * 34 + cA) << 7) + gwA;
            char* dB = smem + ((r * 34 + cB) << 7) + gwB;
            *(uint4*)dA           = uint4{hA[0], hA[1], hA[2], hA[3]};
            *(uint4*)(dA + X2_LO) = uint4{lA[0], lA[1], lA[2], lA[3]};
            *(uint4*)dB           = uint4{hB[0], hB[1], hB[2], hB[3]};
            *(uint4*)(dB + X2_LO) = uint4{lB[0], lB[1], lB[2], lB[3]};
        }
    }
    __syncthreads();                     // BAR1: x2 ready

    // ---- K loop: FULL K per wave (rows 0..2 staged), 12-frag weight window ----
    f32x16 acc;
#pragma unroll
    for (int i = 0; i < 16; ++i) acc[i] = 0.f;

    const char* wbase = wfrag + wmt * 2048 + (size_t)lane * 16;

    __builtin_amdgcn_s_setprio(1);
#pragma unroll
    for (int dj = 0; dj < 3; ++dj) {
        const int c2 = col + dj;
        const int c7 = c2 & 7;
#pragma unroll
        for (int kp = 0; kp < 2; ++kp) {
            bf16x8 wh_[2][3], wl_[2][3];
#pragma unroll
            for (int ksi = 0; ksi < 2; ++ksi) {
#pragma unroll
                for (int di = 0; di < 3; ++di) {
                    const char* wp = wbase + (di * 3 + dj) * 16384 + (kp * 2 + ksi) * 4096;
                    wh_[ksi][di] = *(const bf16x8*)wp;
                    wl_[ksi][di] = *(const bf16x8*)(wp + 1024);
                }
            }
#pragma unroll
            for (int ksi = 0; ksi < 2; ++ksi) {
                const int ks = kp * 2 + ksi;
                const int gg = ((ks * 2 + hs) ^ c7) << 4;
                bf16x8 bh[3], bl[3];
#pragma unroll
                for (int di = 0; di < 3; ++di) {
                    const char* sp = smem + ((di * 34 + c2) << 7) + gg;
                    bh[di] = *(const bf16x8*)sp;
                    bl[di] = *(const bf16x8*)(sp + X2_LO);
                }
#pragma unroll
                for (int di = 0; di < 3; ++di) {
                    acc = __builtin_amdgcn_mfma_f32_32x32x16_bf16(wh_[ksi][di], bh[di], acc, 0, 0, 0);
                    acc = __builtin_amdgcn_mfma_f32_32x32x16_bf16(wh_[ksi][di], bl[di], acc, 0, 0, 0);
                    acc = __builtin_amdgcn_mfma_f32_32x32x16_bf16(wl_[ksi][di], bh[di], acc, 0, 0, 0);
                }
            }
        }
    }
    __builtin_amdgcn_s_setprio(0);

    // ---- tr + raw store (row rt) ----
    float tv[16];
    {
        const size_t obase = ((size_t)b * 64 + wmt * 32) * 1024 + rt * 32 + col;
#pragma unroll
        for (int j = 0; j < 16; ++j) {
            float cp = __cosf(acc[j]);
            float t  = fmaf(TR_C2, cp, TR_C1) / fmaf(TR_C2, cp, TR_C3);
            tv[j] = t;
            int ocl = (j & 3) + 8 * (j >> 2) + 4 * hs;
            out[obase + (size_t)ocl * 1024] = t;
        }
    }

    // ---- per-channel partials: red[64][33] (reuse x2 LDS) ----
    float* red1 = (float*)smem;                    // [64][33]
    float* red2 = red1 + 64 * 33;                  // [64][33]
    __syncthreads();                     // BAR2: kloop LDS reads done
#pragma unroll
    for (int j = 0; j < 16; ++j) {
        int ocl = (j & 3) + 8 * (j >> 2) + 4 * hs;
        int ri  = (wmt * 32 + ocl) * 33 + col;
        red1[ri] = tv[j];
        red2[ri] = tv[j] * tv[j];
    }
    __syncthreads();                     // BAR3
    if (tid < 64) {
        float s1 = 0.f, s2 = 0.f;
#pragma unroll
        for (int p = 0; p < 32; ++p) {
            s1 += red1[tid * 33 + p];
            s2 += red2[tid * 33 + p];
        }
        partials[(size_t)tid * NBLK + bid]        = s1;
        partials[(size_t)(64 + tid) * NBLK + bid] = s2;
    }
}

// ---------------------------------------------------------------------------
// Kernel C: reduce per-block partials -> BN scale/shift. grid 64, block 512.
// ---------------------------------------------------------------------------
__global__ __launch_bounds__(512) void stats_kernel(const float* __restrict__ partials,
                                                    const float* __restrict__ gamma,
                                                    const float* __restrict__ beta,
                                                    float* __restrict__ ss) {
    const int c   = blockIdx.x;          // channel 0..63
    const int tid = threadIdx.x;
    __shared__ float r1[512], r2[512];
    const float* p1 = partials + (size_t)c * NBLK;
    const float* p2 = partials + (size_t)(64 + c) * NBLK;
    r1[tid] = p1[tid] + p1[tid + 512] + p1[tid + 1024] + p1[tid + 1536];
    r2[tid] = p2[tid] + p2[tid + 512] + p2[tid + 1024] + p2[tid + 1536];
    __syncthreads();
#pragma unroll
    for (int s = 256; s > 0; s >>= 1) {
        if (tid < s) {
            r1[tid] += r1[tid + s];
            r2[tid] += r2[tid + s];
        }
        __syncthreads();
    }
    if (tid == 0) {
        const float invN = 1.0f / (float)NPIX;
        float mean = r1[0] * invN;
        float var  = r2[0] * invN - mean * mean;
        float sc   = gamma[c] * rsqrtf(var + BN_EPS);
        ss[c]      = sc;
        ss[64 + c] = beta[c] - mean * sc;
    }
}

// ---------------------------------------------------------------------------
// Kernel D: in-place normalize + clip (float4)
// ---------------------------------------------------------------------------
__global__ __launch_bounds__(256) void norm_kernel(float* __restrict__ out,
                                                   const float* __restrict__ ss) {
    int i = blockIdx.x * 256 + threadIdx.x;
    float4 v = ((float4*)out)[i];
    int oc = (i >> 8) & 63;
    float sc = ss[oc];
    float sh = ss[64 + oc];
    v.x = fminf(1.0f, fmaxf(-1.0f, fmaf(v.x, sc, sh)));
    v.y = fminf(1.0f, fmaxf(-1.0f, fmaf(v.y, sc, sh)));
    v.z = fminf(1.0f, fmaxf(-1.0f, fmaf(v.z, sc, sh)));
    v.w = fminf(1.0f, fmaxf(-1.0f, fmaf(v.w, sc, sh)));
    ((float4*)out)[i] = v;
}

// ---------------------------------------------------------------------------
extern "C" void kernel_launch(void* const* d_in, const int* in_sizes, int n_in,
                              void* d_out, int out_size, void* d_ws, size_t ws_size,
                              hipStream_t stream) {
    const float* x     = (const float*)d_in[0];
    const float* w     = (const float*)d_in[1];
    const float* gamma = (const float*)d_in[2];
    const float* beta  = (const float*)d_in[3];
    float* out = (float*)d_out;

    char*  wfrag    = (char*)d_ws;                          // 147456 B
    float* partials = (float*)((char*)d_ws + 147456);       // 128*2048 floats = 1 MB
    float* ss       = partials + 128 * NBLK;                // 128 floats

    hipLaunchKernelGGL(prep_kernel, dim3(144), dim3(256), 0, stream, w, wfrag);
    hipLaunchKernelGGL(conv_kernel, dim3(32, 64), dim3(128), 0, stream, x, wfrag, out, partials);
    hipLaunchKernelGGL(stats_kernel, dim3(64), dim3(512), 0, stream, partials, gamma, beta, ss);
    hipLaunchKernelGGL(norm_kernel, dim3(4096), dim3(256), 0, stream, out, ss);
}

// Round 15
// 41.395 us; speedup vs baseline: 1.2071x; 1.2071x over previous
//
#include <hip/hip_runtime.h>
#include <hip/hip_cooperative_groups.h>

namespace cg = cooperative_groups;

// ---------------------------------------------------------------------------
// ConvBlock: y = clip(BN(tr(conv3x3(x^2, Wconv))), -1, 1)
// Wconv[oc][c][di][dj] = weight[oc>>3][(c*9+3di+dj)>>3][(oc-(c*9+3di+dj))&7]
// GEMM: A = Wconv (M=64 oc), B = im2col(x^2) (N=65536 px), K=576.
// bf16 MFMA 32x32x16, 3-pass hi/lo split.
// Round 15: RESTORE BEST (round-12 config, 41.085 us): r11 structure
// (256-thr blocks, 4 waves = wmt x kh, 2-row tiles, 1024 blocks, 4/CU)
// + fused BN/clip via cooperative grid sync, de-fused fallback.
// ---------------------------------------------------------------------------

#define A_MORR 0.8578f
#define R_MORR 0.8578f
#define TR_C1 (A_MORR * A_MORR + R_MORR * R_MORR)
#define TR_C2 (-2.0f * A_MORR * R_MORR)
#define TR_C3 (1.0f + (A_MORR * R_MORR) * (A_MORR * R_MORR))
#define BN_EPS 1e-5f

#define NPIX 65536
#define X2_LO 17408          // 4*34*128: lo plane offset
#define SMEM_BYTES 34816
#define NBLK 1024            // conv grid size (16 x 64)

typedef __attribute__((ext_vector_type(8))) short bf16x8;
typedef __attribute__((ext_vector_type(16))) float f32x16;

__device__ __forceinline__ void bf16split(float s, unsigned short& h, unsigned short& l) {
    union { float f; unsigned u; } cv; cv.f = s;
    unsigned r = (cv.u + 0x7fffu + ((cv.u >> 16) & 1u)) & 0xffff0000u;
    h = (unsigned short)(r >> 16);
    union { unsigned u; float f; } hv; hv.u = r;
    float lo = s - hv.f;
    cv.f = lo;
    unsigned r2 = cv.u + 0x7fffu + ((cv.u >> 16) & 1u);
    l = (unsigned short)(r2 >> 16);
}

__device__ __forceinline__ void agst(float* p, float v) {
    __hip_atomic_store(p, v, __ATOMIC_RELAXED, __HIP_MEMORY_SCOPE_AGENT);
}
__device__ __forceinline__ float agld(const float* p) {
    return __hip_atomic_load(p, __ATOMIC_RELAXED, __HIP_MEMORY_SCOPE_AGENT);
}

// ---------------------------------------------------------------------------
// Kernel A: fragment-ready bf16 hi/lo weights.
// wfrag[off*8 + ks*2 + mt][prec][lane][8ch] : 72 * 2048 B
// ---------------------------------------------------------------------------
__global__ __launch_bounds__(256) void prep_kernel(const float* __restrict__ w,
                                                   char* __restrict__ wfrag) {
    int gtid = blockIdx.x * 256 + threadIdx.x;
    if (gtid < 36864) {
        int j    = gtid & 7;
        int lane = (gtid >> 3) & 63;
        int okm  = gtid >> 9;
        int mt   = okm & 1;
        int ks   = (okm >> 1) & 3;
        int off  = okm >> 3;
        int oc   = mt * 32 + (lane & 31);
        int c    = ks * 16 + (lane >> 5) * 8 + j;
        int kg   = c * 9 + off;
        float val = w[(oc >> 3) * 576 + (kg >> 3) * 8 + ((oc - kg) & 7)];
        unsigned short h, l;
        bf16split(val, h, l);
        ((unsigned short*)(wfrag + okm * 2048))[lane * 8 + j] = h;
        ((unsigned short*)(wfrag + okm * 2048 + 1024))[lane * 8 + j] = l;
    }
}

// ---------------------------------------------------------------------------
// Kernel B: MFMA conv + tr (+ fused BN when FUSED=1).
// grid (16,64) = 1024 blocks, block 256 (4 waves: wmt x kh), 4 blocks/CU.
// Block tile: 64 oc x 64 px (2 image rows). After symmetric kh merge each
// wave owns full-K phi of row rt*2+kh and does that row's epilogue.
// LDS x2: [4 rows][34 cols][64 ch] bf16 hi+lo, granule swizzle g = q^(c&7).
// Staging: thread owns one granule (8ch x 1col) -> ds_write_b128 conflict-free.
// ---------------------------------------------------------------------------
template <int FUSED>
__global__ __launch_bounds__(256, 4) void conv_kernel(const float* __restrict__ x,
                                                      const char* __restrict__ wfrag,
                                                      float* __restrict__ out,
                                                      float* __restrict__ partials,
                                                      float* __restrict__ ss,
                                                      const float* __restrict__ gamma,
                                                      const float* __restrict__ beta) {
    const int rt  = blockIdx.x;          // 2-row tile 0..15
    const int b   = blockIdx.y;
    const int bid = b * 16 + rt;         // 0..1023
    const int tid = threadIdx.x;

    const int lane = tid & 63;
    const int wv   = tid >> 6;           // 0..3
    const int wmt  = wv & 1;             // oc half
    const int kh   = wv >> 1;            // K half / owned row
    const int col  = lane & 31;
    const int hs   = lane >> 5;

    __shared__ __align__(16) char smem[SMEM_BYTES];

    // ---- zero halo cols (c=0, c=33) ----
    if (tid < 128) {
        int pr = tid & 1;
        int q  = (tid >> 1) & 7;
        int rc = tid >> 4;               // 0..7
        int r  = rc >> 1;
        int cc = (rc & 1) ? 33 : 0;
        int g  = q ^ (cc & 7);
        *(uint4*)(smem + pr * X2_LO + ((r * 34 + cc) << 7) + (g << 4)) = uint4{0, 0, 0, 0};
    }

    // ---- stage x^2 hi/lo: thread = (col, ch-octet), rows rt*2-1..rt*2+2 ----
    {
        const int co = tid & 31;
        const int qg = tid >> 5;
        const int c  = 1 + co;
        const int gw = (qg ^ (c & 7)) << 4;
        const float* xb = x + (size_t)(b * 64 + qg * 8) * 1024 + co;
#pragma unroll
        for (int r = 0; r < 4; ++r) {
            int gr = rt * 2 - 1 + r;
            float v[8];
#pragma unroll
            for (int j = 0; j < 8; ++j) v[j] = 0.0f;
            if (gr >= 0 && gr < 32) {
#pragma unroll
                for (int j = 0; j < 8; ++j) v[j] = xb[j * 1024 + gr * 32];
            }
            unsigned hp[4], lp[4];
#pragma unroll
            for (int p = 0; p < 4; ++p) {
                unsigned short h0, l0, h1, l1;
                float s0 = v[2 * p] * v[2 * p];
                float s1 = v[2 * p + 1] * v[2 * p + 1];
                bf16split(s0, h0, l0);
                bf16split(s1, h1, l1);
                hp[p] = (unsigned)h0 | ((unsigned)h1 << 16);
                lp[p] = (unsigned)l0 | ((unsigned)l1 << 16);
            }
            char* dst = smem + ((r * 34 + c) << 7) + gw;
            *(uint4*)dst            = uint4{hp[0], hp[1], hp[2], hp[3]};
            *(uint4*)(dst + X2_LO)  = uint4{lp[0], lp[1], lp[2], lp[3]};
        }
    }
    __syncthreads();                     // BAR1: x2 ready

    // ---- K loop: this wave's K-half ----
    f32x16 acc0, acc1;
#pragma unroll
    for (int i = 0; i < 16; ++i) { acc0[i] = 0.f; acc1[i] = 0.f; }

    const char* wbase = wfrag + wmt * 2048 + (size_t)lane * 16;

#pragma unroll
    for (int dj = 0; dj < 3; ++dj) {
        const int c2 = col + dj;
        const int c7 = c2 & 7;
#pragma unroll
        for (int ksi = 0; ksi < 2; ++ksi) {
            const int ks = kh * 2 + ksi;
            const int gg = ((ks * 2 + hs) ^ c7) << 4;
            bf16x8 bh[4], bl[4];
#pragma unroll
            for (int rr = 0; rr < 4; ++rr) {
                const char* sp = smem + ((rr * 34 + c2) << 7) + gg;
                bh[rr] = *(const bf16x8*)sp;
                bl[rr] = *(const bf16x8*)(sp + X2_LO);
            }
#pragma unroll
            for (int di = 0; di < 3; ++di) {
                const char* wp = wbase + (di * 3 + dj) * 16384 + ks * 4096;
                bf16x8 ah = *(const bf16x8*)wp;
                bf16x8 al = *(const bf16x8*)(wp + 1024);
                acc0 = __builtin_amdgcn_mfma_f32_32x32x16_bf16(ah, bh[di],     acc0, 0, 0, 0);
                acc1 = __builtin_amdgcn_mfma_f32_32x32x16_bf16(ah, bh[di + 1], acc1, 0, 0, 0);
                acc0 = __builtin_amdgcn_mfma_f32_32x32x16_bf16(ah, bl[di],     acc0, 0, 0, 0);
                acc1 = __builtin_amdgcn_mfma_f32_32x32x16_bf16(ah, bl[di + 1], acc1, 0, 0, 0);
                acc0 = __builtin_amdgcn_mfma_f32_32x32x16_bf16(al, bh[di],     acc0, 0, 0, 0);
                acc1 = __builtin_amdgcn_mfma_f32_32x32x16_bf16(al, bh[di + 1], acc1, 0, 0, 0);
            }
        }
    }

    // ---- symmetric kh merge: each wave ends with full-K phi of row kh ----
    float* mg = (float*)smem;            // 4 slots x 16 x 64 floats
    __syncthreads();                     // BAR2: x2 reads done
    {
        const int wslot = wmt * 2 + kh;
        if (kh == 0) {
#pragma unroll
            for (int j = 0; j < 16; ++j) mg[(wslot * 16 + j) * 64 + lane] = acc1[j];
        } else {
#pragma unroll
            for (int j = 0; j < 16; ++j) mg[(wslot * 16 + j) * 64 + lane] = acc0[j];
        }
    }
    __syncthreads();                     // BAR3
    f32x16 phi;
    {
        const int rslot = wmt * 2 + (kh ^ 1);
        if (kh == 0) {
#pragma unroll
            for (int j = 0; j < 16; ++j) phi[j] = acc0[j] + mg[(rslot * 16 + j) * 64 + lane];
        } else {
#pragma unroll
            for (int j = 0; j < 16; ++j) phi[j] = acc1[j] + mg[(rslot * 16 + j) * 64 + lane];
        }
    }

    // ---- tr (kept in registers) ----
    float tv[16];
#pragma unroll
    for (int j = 0; j < 16; ++j) {
        float cp = __cosf(phi[j]);
        tv[j] = fmaf(TR_C2, cp, TR_C1) / fmaf(TR_C2, cp, TR_C3);
    }

    // ---- per-channel partials: red[64][66] ----
    float* red1 = (float*)smem;                    // [64][66]
    float* red2 = red1 + 64 * 66;                  // [64][66]
    __syncthreads();                     // BAR4: merge reads done
#pragma unroll
    for (int j = 0; j < 16; ++j) {
        int ocl = (j & 3) + 8 * (j >> 2) + 4 * hs;
        int ri  = (wmt * 32 + ocl) * 66 + kh * 33 + col;
        red1[ri] = tv[j];
        red2[ri] = tv[j] * tv[j];
    }
    __syncthreads();                     // BAR5
    if (tid < 64) {
        float s1 = 0.f, s2 = 0.f;
#pragma unroll
        for (int k = 0; k < 64; ++k) {
            int idx = tid * 66 + (k >> 5) * 33 + (k & 31);
            s1 += red1[idx];
            s2 += red2[idx];
        }
        if (FUSED) {
            agst(&partials[(size_t)tid * NBLK + bid], s1);
            agst(&partials[(size_t)(64 + tid) * NBLK + bid], s2);
        } else {
            partials[(size_t)tid * NBLK + bid]        = s1;
            partials[(size_t)(64 + tid) * NBLK + bid] = s2;
        }
    }

    if constexpr (FUSED) {
        // ---- sync 1: all partials visible; blocks 0..63 reduce one channel ----
        cg::this_grid().sync();
        if (bid < 64) {
            float s1 = 0.f, s2 = 0.f;
            for (int k = tid; k < NBLK; k += 256) {
                s1 += agld(&partials[(size_t)bid * NBLK + k]);
                s2 += agld(&partials[(size_t)(64 + bid) * NBLK + k]);
            }
            float* q1 = (float*)smem;          // 256
            float* q2 = q1 + 256;              // 256
            q1[tid] = s1;
            q2[tid] = s2;
            __syncthreads();
#pragma unroll
            for (int s = 128; s > 0; s >>= 1) {
                if (tid < s) { q1[tid] += q1[tid + s]; q2[tid] += q2[tid + s]; }
                __syncthreads();
            }
            if (tid == 0) {
                const float invN = 1.0f / (float)NPIX;
                float mean = q1[0] * invN;
                float var  = q2[0] * invN - mean * mean;
                float sc   = gamma[bid] * rsqrtf(var + BN_EPS);
                agst(&ss[bid], sc);
                agst(&ss[64 + bid], beta[bid] - mean * sc);
            }
        }
        // ---- sync 2: ss ready; normalize in-register, store once ----
        cg::this_grid().sync();
        float* ssb = (float*)(smem + 33792);       // 128 floats
        if (tid < 128) ssb[tid] = agld(&ss[tid]);
        __syncthreads();

        const size_t obase = ((size_t)b * 64 + wmt * 32) * 1024 + (rt * 2 + kh) * 32 + col;
#pragma unroll
        for (int j = 0; j < 16; ++j) {
            int ocl  = (j & 3) + 8 * (j >> 2) + 4 * hs;
            float sc = ssb[wmt * 32 + ocl];
            float sh = ssb[64 + wmt * 32 + ocl];
            float y  = fminf(1.0f, fmaxf(-1.0f, fmaf(tv[j], sc, sh)));
            out[obase + (size_t)ocl * 1024] = y;
        }
    } else {
        // ---- store raw tr; BN applied by separate kernels ----
        const size_t obase = ((size_t)b * 64 + wmt * 32) * 1024 + (rt * 2 + kh) * 32 + col;
#pragma unroll
        for (int j = 0; j < 16; ++j) {
            int ocl = (j & 3) + 8 * (j >> 2) + 4 * hs;
            out[obase + (size_t)ocl * 1024] = tv[j];
        }
    }
}

// ---------------------------------------------------------------------------
// Fallback kernels
// ---------------------------------------------------------------------------
__global__ __launch_bounds__(512) void stats_kernel(const float* __restrict__ partials,
                                                    const float* __restrict__ gamma,
                                                    const float* __restrict__ beta,
                                                    float* __restrict__ ss) {
    const int c   = blockIdx.x;
    const int tid = threadIdx.x;
    __shared__ float r1[512], r2[512];
    r1[tid] = partials[(size_t)c * NBLK + tid] + partials[(size_t)c * NBLK + 512 + tid];
    r2[tid] = partials[(size_t)(64 + c) * NBLK + tid]
            + partials[(size_t)(64 + c) * NBLK + 512 + tid];
    __syncthreads();
#pragma unroll
    for (int s = 256; s > 0; s >>= 1) {
        if (tid < s) { r1[tid] += r1[tid + s]; r2[tid] += r2[tid + s]; }
        __syncthreads();
    }
    if (tid == 0) {
        const float invN = 1.0f / (float)NPIX;
        float mean = r1[0] * invN;
        float var  = r2[0] * invN - mean * mean;
        float sc   = gamma[c] * rsqrtf(var + BN_EPS);
        ss[c]      = sc;
        ss[64 + c] = beta[c] - mean * sc;
    }
}

__global__ __launch_bounds__(256) void norm_kernel(float* __restrict__ out,
                                                   const float* __restrict__ ss) {
    int i = blockIdx.x * 256 + threadIdx.x;
    float4 v = ((float4*)out)[i];
    int oc = (i >> 8) & 63;
    float sc = ss[oc];
    float sh = ss[64 + oc];
    v.x = fminf(1.0f, fmaxf(-1.0f, fmaf(v.x, sc, sh)));
    v.y = fminf(1.0f, fmaxf(-1.0f, fmaf(v.y, sc, sh)));
    v.z = fminf(1.0f, fmaxf(-1.0f, fmaf(v.z, sc, sh)));
    v.w = fminf(1.0f, fmaxf(-1.0f, fmaf(v.w, sc, sh)));
    ((float4*)out)[i] = v;
}

// ---------------------------------------------------------------------------
extern "C" void kernel_launch(void* const* d_in, const int* in_sizes, int n_in,
                              void* d_out, int out_size, void* d_ws, size_t ws_size,
                              hipStream_t stream) {
    const float* x     = (const float*)d_in[0];
    const float* w     = (const float*)d_in[1];
    const float* gamma = (const float*)d_in[2];
    const float* beta  = (const float*)d_in[3];
    float* out = (float*)d_out;

    char*  wfrag    = (char*)d_ws;                          // 147456 B
    float* partials = (float*)((char*)d_ws + 147456);       // 128*1024 floats
    float* ss       = partials + 128 * NBLK;                // 128 floats

    hipLaunchKernelGGL(prep_kernel, dim3(144), dim3(256), 0, stream, w, wfrag);

    int maxb = 0;
    hipError_t qe = hipOccupancyMaxActiveBlocksPerMultiprocessor(
        &maxb, reinterpret_cast<const void*>(&conv_kernel<1>), 256, 0);
    bool fused = (qe == hipSuccess) && (maxb >= 4);

    if (fused) {
        void* cargs[] = { (void*)&x, (void*)&wfrag, (void*)&out, (void*)&partials,
                          (void*)&ss, (void*)&gamma, (void*)&beta };
        hipError_t le = hipLaunchCooperativeKernel(
            reinterpret_cast<const void*>(&conv_kernel<1>),
            dim3(16, 64), dim3(256), cargs, 0, stream);
        if (le != hipSuccess) fused = false;
    }
    if (!fused) {
        hipLaunchKernelGGL(conv_kernel<0>, dim3(16, 64), dim3(256), 0, stream,
                           x, wfrag, out, partials, ss, gamma, beta);
        hipLaunchKernelGGL(stats_kernel, dim3(64), dim3(512), 0, stream,
                           partials, gamma, beta, ss);
        hipLaunchKernelGGL(norm_kernel, dim3(4096), dim3(256), 0, stream, out, ss);
    }
}